// Round 1
// baseline (2720.646 us; speedup 1.0000x reference)
//
#include <hip/hip_runtime.h>
#include <math.h>

#define NBATCH 512
#define NPTS   128
#define KNN    20
#define NFEAT  16

typedef unsigned char uchar;

// ---------------- block-level stats reduction -> global double atomics ----------------
template<int C>
__device__ inline void block_stats_atomic(const float* ls, const float* lq,
                                          double* __restrict__ gsum, double* __restrict__ gsq){
  __shared__ float ssum[C];
  __shared__ float ssq[C];
  const int t = threadIdx.x;
  if (t < C){ ssum[t] = 0.f; ssq[t] = 0.f; }
  __syncthreads();
  #pragma unroll
  for (int c = 0; c < C; ++c){
    float a = ls[c], b = lq[c];
    #pragma unroll
    for (int m = 32; m; m >>= 1){ a += __shfl_xor(a, m, 64); b += __shfl_xor(b, m, 64); }
    if ((t & 63) == 0){ atomicAdd(&ssum[c], a); atomicAdd(&ssq[c], b); }
  }
  __syncthreads();
  if (t < C){
    unsafeAtomicAdd(&gsum[t], (double)ssum[t]);
    unsafeAtomicAdd(&gsq[t],  (double)ssq[t]);
  }
  __syncthreads();  // guard LDS reuse across repeated calls
}

// ---------------- KNN on 2-D points ----------------
__global__ __launch_bounds__(128) void knn1_kernel(const float* __restrict__ pts,
                                                   uchar* __restrict__ idx_out){
  const int b = blockIdx.x, t = threadIdx.x;
  __shared__ float px[NPTS], py[NPTS], sq[NPTS];
  const float* p = pts + (size_t)b * NPTS * 2;
  const float x = p[2*t], y = p[2*t+1];
  px[t] = x; py[t] = y; sq[t] = x*x + y*y;
  __syncthreads();
  const float sqt = sq[t];
  float bd[KNN]; int bi[KNN];
  #pragma unroll
  for (int q = 0; q < KNN; ++q){ bd[q] = 3.0e38f; bi[q] = 0; }
  for (int j = 0; j < NPTS; ++j){
    float d = sqt + sq[j] - 2.0f*(x*px[j] + y*py[j]);
    if (j == t) d += 1.0e9f;
    float cd = d; int ci = j;
    #pragma unroll
    for (int q = 0; q < KNN; ++q){
      if (cd < bd[q]){ float td=bd[q]; bd[q]=cd; cd=td; int ti=bi[q]; bi[q]=ci; ci=ti; }
    }
  }
  uchar* o = idx_out + (size_t)(b*NPTS + t) * KNN;
  #pragma unroll
  for (int q = 0; q < KNN; ++q) o[q] = (uchar)bi[q];
}

// ---------------- KNN on 32-D features ----------------
__global__ __launch_bounds__(128) void knn2_kernel(const float* __restrict__ x1,
                                                   uchar* __restrict__ idx_out){
  const int b = blockIdx.x, t = threadIdx.x;
  __shared__ float xs[NPTS][33];   // +1 pad: avoid 64-way LDS bank conflict
  __shared__ float sq[NPTS];
  const float* xb = x1 + (size_t)b * NPTS * 32;
  float s = 0.f;
  float xt[32];
  #pragma unroll
  for (int c = 0; c < 32; ++c){ float v = xb[t*32+c]; xs[t][c] = v; xt[c] = v; s += v*v; }
  sq[t] = s;
  __syncthreads();
  const float sqt = sq[t];
  float bd[KNN]; int bi[KNN];
  #pragma unroll
  for (int q = 0; q < KNN; ++q){ bd[q] = 3.0e38f; bi[q] = 0; }
  for (int j = 0; j < NPTS; ++j){
    float dot = 0.f;
    #pragma unroll
    for (int c = 0; c < 32; ++c) dot = fmaf(xt[c], xs[j][c], dot);  // xs[j][*]: broadcast read
    float d = sqt + sq[j] - 2.0f*dot;
    if (j == t) d += 1.0e9f;
    float cd = d; int ci = j;
    #pragma unroll
    for (int q = 0; q < KNN; ++q){
      if (cd < bd[q]){ float td=bd[q]; bd[q]=cd; cd=td; int ti=bi[q]; bi[q]=ci; ci=ti; }
    }
  }
  uchar* o = idx_out + (size_t)(b*NPTS + t) * KNN;
  #pragma unroll
  for (int q = 0; q < KNN; ++q) o[q] = (uchar)bi[q];
}

// ---------------- BN finalize: scale/shift from accumulated sums ----------------
__global__ void bn_finalize(const double* __restrict__ stat, const float* __restrict__ g,
                            const float* __restrict__ be, float* __restrict__ sc,
                            float* __restrict__ sh, int C, double inv_n){
  const int c = threadIdx.x;
  if (c < C){
    const double m = stat[c] * inv_n;
    const double v = stat[C + c] * inv_n - m*m;
    const float s = (float)((double)g[c] / sqrt(v + 1e-5));
    sc[c] = s;
    sh[c] = be[c] - (float)m * s;
  }
}

// ---------------- EdgeConv1 pass 1: stats of h1 = e @ W1 + b1 ----------------
__global__ __launch_bounds__(256) void ec1_pass1(
    const float* __restrict__ feat, const uchar* __restrict__ idx,
    const float* __restrict__ W1, const float* __restrict__ B1,
    double* __restrict__ stat){
  const int gt = blockIdx.x*256 + threadIdx.x;
  const int b = gt >> 7, n = gt & (NPTS-1);
  const float* Xb = feat + (size_t)b * NPTS * NFEAT;
  float xi[NFEAT];
  #pragma unroll
  for (int i = 0; i < NFEAT; ++i) xi[i] = Xb[n*NFEAT + i];
  float hb[32];
  #pragma unroll
  for (int c = 0; c < 32; ++c) hb[c] = B1[c];
  #pragma unroll
  for (int i = 0; i < NFEAT; ++i){
    const float v = xi[i];
    #pragma unroll
    for (int c = 0; c < 32; ++c) hb[c] = fmaf(v, W1[i*32 + c], hb[c]);
  }
  const uchar* id = idx + (size_t)(b*NPTS + n) * KNN;
  float ls[32], lq[32];
  #pragma unroll
  for (int c = 0; c < 32; ++c){ ls[c] = 0.f; lq[c] = 0.f; }
  for (int k = 0; k < KNN; ++k){
    const int j = id[k];
    float h[32];
    #pragma unroll
    for (int c = 0; c < 32; ++c) h[c] = hb[c];
    #pragma unroll
    for (int i = 0; i < NFEAT; ++i){
      const float d = Xb[j*NFEAT + i] - xi[i];
      #pragma unroll
      for (int c = 0; c < 32; ++c) h[c] = fmaf(d, W1[(NFEAT+i)*32 + c], h[c]);
    }
    #pragma unroll
    for (int c = 0; c < 32; ++c){ ls[c] += h[c]; lq[c] = fmaf(h[c], h[c], lq[c]); }
  }
  block_stats_atomic<32>(ls, lq, stat, stat + 32);
}

// ---------------- EdgeConv1 pass 2: recompute h1, BN+ReLU, h2 = .@W2+b2, stats of h2 ----------------
__global__ __launch_bounds__(256) void ec1_pass2(
    const float* __restrict__ feat, const uchar* __restrict__ idx,
    const float* __restrict__ W1, const float* __restrict__ B1,
    const float* __restrict__ sc1, const float* __restrict__ sh1,
    const float* __restrict__ W2, const float* __restrict__ B2,
    double* __restrict__ stat){
  const int gt = blockIdx.x*256 + threadIdx.x;
  const int b = gt >> 7, n = gt & (NPTS-1);
  const float* Xb = feat + (size_t)b * NPTS * NFEAT;
  float xi[NFEAT];
  #pragma unroll
  for (int i = 0; i < NFEAT; ++i) xi[i] = Xb[n*NFEAT + i];
  float hb[32];
  #pragma unroll
  for (int c = 0; c < 32; ++c) hb[c] = B1[c];
  #pragma unroll
  for (int i = 0; i < NFEAT; ++i){
    const float v = xi[i];
    #pragma unroll
    for (int c = 0; c < 32; ++c) hb[c] = fmaf(v, W1[i*32 + c], hb[c]);
  }
  const uchar* id = idx + (size_t)(b*NPTS + n) * KNN;
  float ls[32], lq[32];
  #pragma unroll
  for (int c = 0; c < 32; ++c){ ls[c] = 0.f; lq[c] = 0.f; }
  for (int k = 0; k < KNN; ++k){
    const int j = id[k];
    float h[32];
    #pragma unroll
    for (int c = 0; c < 32; ++c) h[c] = hb[c];
    #pragma unroll
    for (int i = 0; i < NFEAT; ++i){
      const float d = Xb[j*NFEAT + i] - xi[i];
      #pragma unroll
      for (int c = 0; c < 32; ++c) h[c] = fmaf(d, W1[(NFEAT+i)*32 + c], h[c]);
    }
    #pragma unroll
    for (int c = 0; c < 32; ++c) h[c] = fmaxf(fmaf(h[c], sc1[c], sh1[c]), 0.f);
    float h2[32];
    #pragma unroll
    for (int c = 0; c < 32; ++c) h2[c] = B2[c];
    #pragma unroll
    for (int i = 0; i < 32; ++i){
      const float v = h[i];
      #pragma unroll
      for (int c = 0; c < 32; ++c) h2[c] = fmaf(v, W2[i*32 + c], h2[c]);
    }
    #pragma unroll
    for (int c = 0; c < 32; ++c){ ls[c] += h2[c]; lq[c] = fmaf(h2[c], h2[c], lq[c]); }
  }
  block_stats_atomic<32>(ls, lq, stat, stat + 32);
}

// ---------------- EdgeConv1 pass 3: full mlp1, mean over k -> x1 ----------------
__global__ __launch_bounds__(256) void ec1_pass3(
    const float* __restrict__ feat, const uchar* __restrict__ idx,
    const float* __restrict__ W1, const float* __restrict__ B1,
    const float* __restrict__ sc1, const float* __restrict__ sh1,
    const float* __restrict__ W2, const float* __restrict__ B2,
    const float* __restrict__ sc2, const float* __restrict__ sh2,
    const float* __restrict__ W3, const float* __restrict__ B3,
    float* __restrict__ x1){
  const int gt = blockIdx.x*256 + threadIdx.x;
  const int b = gt >> 7, n = gt & (NPTS-1);
  const float* Xb = feat + (size_t)b * NPTS * NFEAT;
  float xi[NFEAT];
  #pragma unroll
  for (int i = 0; i < NFEAT; ++i) xi[i] = Xb[n*NFEAT + i];
  float hb[32];
  #pragma unroll
  for (int c = 0; c < 32; ++c) hb[c] = B1[c];
  #pragma unroll
  for (int i = 0; i < NFEAT; ++i){
    const float v = xi[i];
    #pragma unroll
    for (int c = 0; c < 32; ++c) hb[c] = fmaf(v, W1[i*32 + c], hb[c]);
  }
  const uchar* id = idx + (size_t)(b*NPTS + n) * KNN;
  float acc[32];
  #pragma unroll
  for (int c = 0; c < 32; ++c) acc[c] = 0.f;
  for (int k = 0; k < KNN; ++k){
    const int j = id[k];
    float h[32];
    #pragma unroll
    for (int c = 0; c < 32; ++c) h[c] = hb[c];
    #pragma unroll
    for (int i = 0; i < NFEAT; ++i){
      const float d = Xb[j*NFEAT + i] - xi[i];
      #pragma unroll
      for (int c = 0; c < 32; ++c) h[c] = fmaf(d, W1[(NFEAT+i)*32 + c], h[c]);
    }
    #pragma unroll
    for (int c = 0; c < 32; ++c) h[c] = fmaxf(fmaf(h[c], sc1[c], sh1[c]), 0.f);
    float h2[32];
    #pragma unroll
    for (int c = 0; c < 32; ++c) h2[c] = B2[c];
    #pragma unroll
    for (int i = 0; i < 32; ++i){
      const float v = h[i];
      #pragma unroll
      for (int c = 0; c < 32; ++c) h2[c] = fmaf(v, W2[i*32 + c], h2[c]);
    }
    #pragma unroll
    for (int c = 0; c < 32; ++c) h2[c] = fmaxf(fmaf(h2[c], sc2[c], sh2[c]), 0.f);
    #pragma unroll
    for (int i = 0; i < 32; ++i){
      const float v = h2[i];
      #pragma unroll
      for (int c = 0; c < 32; ++c) acc[c] = fmaf(v, W3[i*32 + c], acc[c]);
    }
  }
  float* o = x1 + (size_t)(b*NPTS + n) * 32;
  #pragma unroll
  for (int c = 0; c < 32; ++c) o[c] = acc[c] * (1.0f/KNN) + B3[c];
}

// ---------------- EdgeConv2 pass 1: stats of h4 (channel-halved to limit VGPRs) ----------------
__global__ __launch_bounds__(256) void ec2_pass1(
    const float* __restrict__ x1, const uchar* __restrict__ idx,
    const float* __restrict__ W4, const float* __restrict__ B4,
    double* __restrict__ stat){  // layout: [sum 64][sq 64]
  const int gt = blockIdx.x*256 + threadIdx.x;
  const int b = gt >> 7, n = gt & (NPTS-1);
  const float* Xb = x1 + (size_t)b * NPTS * 32;
  float xi[32];
  #pragma unroll
  for (int i = 0; i < 32; ++i) xi[i] = Xb[n*32 + i];
  const uchar* id = idx + (size_t)(b*NPTS + n) * KNN;
  for (int half = 0; half < 2; ++half){   // uniform across block
    const int co = half * 32;
    float hb[32];
    #pragma unroll
    for (int c = 0; c < 32; ++c) hb[c] = B4[co + c];
    #pragma unroll
    for (int i = 0; i < 32; ++i){
      const float v = xi[i];
      #pragma unroll
      for (int c = 0; c < 32; ++c) hb[c] = fmaf(v, W4[i*64 + co + c], hb[c]);
    }
    float ls[32], lq[32];
    #pragma unroll
    for (int c = 0; c < 32; ++c){ ls[c] = 0.f; lq[c] = 0.f; }
    for (int k = 0; k < KNN; ++k){
      const int j = id[k];
      float h[32];
      #pragma unroll
      for (int c = 0; c < 32; ++c) h[c] = hb[c];
      #pragma unroll
      for (int i = 0; i < 32; ++i){
        const float d = Xb[j*32 + i] - xi[i];
        #pragma unroll
        for (int c = 0; c < 32; ++c) h[c] = fmaf(d, W4[(32+i)*64 + co + c], h[c]);
      }
      #pragma unroll
      for (int c = 0; c < 32; ++c){ ls[c] += h[c]; lq[c] = fmaf(h[c], h[c], lq[c]); }
    }
    block_stats_atomic<32>(ls, lq, stat + co, stat + 64 + co);
  }
}

// ---------------- EdgeConv2 pass 2: full mlp2, mean over k -> x2 ----------------
__global__ __launch_bounds__(256) void ec2_pass2(
    const float* __restrict__ x1, const uchar* __restrict__ idx,
    const float* __restrict__ W4, const float* __restrict__ B4,
    const float* __restrict__ sc4, const float* __restrict__ sh4,
    const float* __restrict__ W5, const float* __restrict__ B5,
    float* __restrict__ x2){
  const int gt = blockIdx.x*256 + threadIdx.x;
  const int b = gt >> 7, n = gt & (NPTS-1);
  const float* Xb = x1 + (size_t)b * NPTS * 32;
  float xi[32];
  #pragma unroll
  for (int i = 0; i < 32; ++i) xi[i] = Xb[n*32 + i];
  float hb[64];
  #pragma unroll
  for (int c = 0; c < 64; ++c) hb[c] = B4[c];
  #pragma unroll
  for (int i = 0; i < 32; ++i){
    const float v = xi[i];
    #pragma unroll
    for (int c = 0; c < 64; ++c) hb[c] = fmaf(v, W4[i*64 + c], hb[c]);
  }
  float acc[64];
  #pragma unroll
  for (int c = 0; c < 64; ++c) acc[c] = 0.f;
  const uchar* id = idx + (size_t)(b*NPTS + n) * KNN;
  for (int k = 0; k < KNN; ++k){
    const int j = id[k];
    float h[64];
    #pragma unroll
    for (int c = 0; c < 64; ++c) h[c] = hb[c];
    #pragma unroll
    for (int i = 0; i < 32; ++i){
      const float d = Xb[j*32 + i] - xi[i];
      #pragma unroll
      for (int c = 0; c < 64; ++c) h[c] = fmaf(d, W4[(32+i)*64 + c], h[c]);
    }
    #pragma unroll
    for (int c = 0; c < 64; ++c) h[c] = fmaxf(fmaf(h[c], sc4[c], sh4[c]), 0.f);
    #pragma unroll
    for (int i = 0; i < 64; ++i){
      const float v = h[i];
      #pragma unroll
      for (int c = 0; c < 64; ++c) acc[c] = fmaf(v, W5[i*64 + c], acc[c]);
    }
  }
  float* o = x2 + (size_t)(b*NPTS + n) * 64;
  #pragma unroll
  for (int c = 0; c < 64; ++c) o[c] = acc[c] * (1.0f/KNN) + B5[c];
}

// ---------------- global max over N + head MLP ----------------
__global__ __launch_bounds__(128) void head_kernel(const float* __restrict__ x2,
    const float* __restrict__ w1, const float* __restrict__ b1,
    const float* __restrict__ w2, const float* __restrict__ b2,
    const float* __restrict__ w3, const float* __restrict__ b3,
    float* __restrict__ out){
  const int b = blockIdx.x, t = threadIdx.x;
  __shared__ float gmax[64];
  __shared__ float h1s[128];
  __shared__ float part[2];
  if (t < 64){
    const float* xb = x2 + (size_t)b * NPTS * 64 + t;
    float m = -3.0e38f;
    for (int n = 0; n < NPTS; ++n) m = fmaxf(m, xb[n*64]);
    gmax[t] = m;
  }
  __syncthreads();
  float a = b1[t];
  #pragma unroll
  for (int i = 0; i < 64; ++i) a = fmaf(gmax[i], w1[i*128 + t], a);
  h1s[t] = fmaxf(a, 0.f);
  __syncthreads();
  float h2 = b2[t];
  #pragma unroll
  for (int i = 0; i < 128; ++i) h2 = fmaf(h1s[i], w2[i*128 + t], h2);
  h2 = fmaxf(h2, 0.f);
  float p = h2 * w3[t];
  #pragma unroll
  for (int m = 32; m; m >>= 1) p += __shfl_xor(p, m, 64);
  if ((t & 63) == 0) part[t >> 6] = p;
  __syncthreads();
  if (t == 0) out[b] = part[0] + part[1] + b3[0];
}

extern "C" void kernel_launch(void* const* d_in, const int* in_sizes, int n_in,
                              void* d_out, int out_size, void* d_ws, size_t ws_size,
                              hipStream_t stream) {
  const float* points = (const float*)d_in[0];
  const float* feat   = (const float*)d_in[1];
  const float* c1_w1  = (const float*)d_in[2];
  const float* c1_b1  = (const float*)d_in[3];
  const float* c1_g1  = (const float*)d_in[4];
  const float* c1_be1 = (const float*)d_in[5];
  const float* c1_w2  = (const float*)d_in[6];
  const float* c1_b2  = (const float*)d_in[7];
  const float* c1_g2  = (const float*)d_in[8];
  const float* c1_be2 = (const float*)d_in[9];
  const float* c1_w3  = (const float*)d_in[10];
  const float* c1_b3  = (const float*)d_in[11];
  const float* c2_w1  = (const float*)d_in[12];
  const float* c2_b1  = (const float*)d_in[13];
  const float* c2_g1  = (const float*)d_in[14];
  const float* c2_be1 = (const float*)d_in[15];
  const float* c2_w2  = (const float*)d_in[16];
  const float* c2_b2  = (const float*)d_in[17];
  const float* m_w1   = (const float*)d_in[18];
  const float* m_b1   = (const float*)d_in[19];
  const float* m_w2   = (const float*)d_in[20];
  const float* m_b2   = (const float*)d_in[21];
  const float* m_w3   = (const float*)d_in[22];
  const float* m_b3   = (const float*)d_in[23];
  float* out = (float*)d_out;

  char* ws = (char*)d_ws;
  const size_t NEDGE = (size_t)NBATCH * NPTS * KNN;      // 1,310,720
  uchar*  idx1 = (uchar*)ws;                              // 1,310,720 B
  uchar*  idx2 = (uchar*)(ws + NEDGE);                    // 1,310,720 B
  float*  x1   = (float*)(ws + 2*NEDGE);                  // 8,388,608 B
  float*  x2   = (float*)(ws + 2*NEDGE + (size_t)NBATCH*NPTS*32*4);  // 16,777,216 B
  double* stats = (double*)(ws + 2*NEDGE + (size_t)NBATCH*NPTS*(32+64)*4);
  float*  scales = (float*)((char*)stats + 256*sizeof(double));
  // stats layout: [h1 sum32 | h1 sq32][h2 sum32 | h2 sq32][h4 sum64 | h4 sq64]
  double* st1 = stats;
  double* st2 = stats + 64;
  double* st4 = stats + 128;
  float* sc1 = scales;       float* sh1 = scales + 32;
  float* sc2 = scales + 64;  float* sh2 = scales + 96;
  float* sc4 = scales + 128; float* sh4 = scales + 192;

  const double inv_n = 1.0 / (double)NEDGE;

  hipMemsetAsync(stats, 0, 256*sizeof(double), stream);

  knn1_kernel<<<NBATCH, 128, 0, stream>>>(points, idx1);
  ec1_pass1<<<256, 256, 0, stream>>>(feat, idx1, c1_w1, c1_b1, st1);
  bn_finalize<<<1, 32, 0, stream>>>(st1, c1_g1, c1_be1, sc1, sh1, 32, inv_n);
  ec1_pass2<<<256, 256, 0, stream>>>(feat, idx1, c1_w1, c1_b1, sc1, sh1, c1_w2, c1_b2, st2);
  bn_finalize<<<1, 32, 0, stream>>>(st2, c1_g2, c1_be2, sc2, sh2, 32, inv_n);
  ec1_pass3<<<256, 256, 0, stream>>>(feat, idx1, c1_w1, c1_b1, sc1, sh1, c1_w2, c1_b2,
                                     sc2, sh2, c1_w3, c1_b3, x1);
  knn2_kernel<<<NBATCH, 128, 0, stream>>>(x1, idx2);
  ec2_pass1<<<256, 256, 0, stream>>>(x1, idx2, c2_w1, c2_b1, st4);
  bn_finalize<<<1, 64, 0, stream>>>(st4, c2_g1, c2_be1, sc4, sh4, 64, inv_n);
  ec2_pass2<<<256, 256, 0, stream>>>(x1, idx2, c2_w1, c2_b1, sc4, sh4, c2_w2, c2_b2, x2);
  head_kernel<<<NBATCH, 128, 0, stream>>>(x2, m_w1, m_b1, m_w2, m_b2, m_w3, m_b3, out);
}